// Round 5
// baseline (2678.744 us; speedup 1.0000x reference)
//
#include <hip/hip_runtime.h>
#include <stdint.h>

typedef _Float16 f16;
typedef _Float16 f16x8 __attribute__((ext_vector_type(8)));
typedef float f32x4 __attribute__((ext_vector_type(4)));

#define INF_F __builtin_inff()
#define KM 24   // merge candidate margin

__device__ __forceinline__ bool lexLess(float s1, int n1, float s2, int n2) {
    return (s1 < s2) || (s1 == s2 && n1 < n2);
}

#define GLOAD_LDS16(gsrc, ldst)                                                  \
    __builtin_amdgcn_global_load_lds(                                            \
        (const __attribute__((address_space(1))) uint32_t*)(gsrc),               \
        (__attribute__((address_space(3))) uint32_t*)(ldst), 16, 0, 0)

// ---------------------------------------------------------------------------
// Kernel 0: pack brep [64,512] f32 -> f16 MFMA A-fragments, COALESCED layout:
// xfrag[(ks*4+ms)*64 + lane] = uint4 of A[m=ms*16+(lane&15)]
// [k = ks*32 + (lane>>4)*8 + j], j=0..7.  Lane-contiguous 1KB per (ks,ms).
// ---------------------------------------------------------------------------
__global__ __launch_bounds__(256) void prepack_kernel(
    const float* __restrict__ brep, uint4* __restrict__ xfrag)
{
    const int e = blockIdx.x * 256 + threadIdx.x;   // 0..4095
    if (e >= 4096) return;
    const int lane = e & 63;
    const int ms = (e >> 6) & 3;
    const int ks = e >> 8;
    const int m = ms * 16 + (lane & 15);
    const int k = ks * 32 + (lane >> 4) * 8;
    const float* src = brep + m * 512 + k;
    unsigned short hb[8];
    #pragma unroll
    for (int j = 0; j < 8; j++) {
        f16 v = (f16)src[j];                         // RTN
        hb[j] = __builtin_bit_cast(unsigned short, v);
    }
    uint4 o;
    o.x = (unsigned)hb[0] | ((unsigned)hb[1] << 16);
    o.y = (unsigned)hb[2] | ((unsigned)hb[3] << 16);
    o.z = (unsigned)hb[4] | ((unsigned)hb[5] << 16);
    o.w = (unsigned)hb[6] | ((unsigned)hb[7] << 16);
    xfrag[e] = o;
}

// ---------------------------------------------------------------------------
// Kernel 1: 512 threads / 8 waves, 128-row tiles. A-fragments live in LDS
// (filled once per block via global_load_lds; conflict-free ds_read_b128).
// Per tile, each lane bursts its row-slice (32 float4 = 2KB-per-row across
// 4 q-lanes) into registers -> 16 MFMA k-steps with cvt_pkrtz f32->f16.
// s = ||y||^2 - 2 x.y through slds [n][m]; 64 scanners keep exact per-block
// top-16 per batch row (lexicographic (s, idx)).
// ---------------------------------------------------------------------------
__global__ __launch_bounds__(512, 2) void dist_topk_kernel(
    const float* __restrict__ reps, const uint4* __restrict__ xfrag,
    float* __restrict__ cs, int* __restrict__ ci,
    int N, int tilesBase, int tilesRem)
{
    __shared__ uint4 afr[4096];                      // 64 KB A-fragments
    __shared__ __align__(16) float slds[128][68];    // 34.8 KB
    __shared__ float topd[16][64];
    __shared__ int   topi[16][64];

    const int tid = threadIdx.x;
    const int w = tid >> 6, lane = tid & 63;
    const int li = lane & 15, q = lane >> 4;
    const int b = blockIdx.x;
    const int t0 = b * tilesBase + min(b, tilesRem);
    const int tcount = tilesBase + (b < tilesRem ? 1 : 0);

    // ---- one-time: fill A-fragment LDS (coalesced, linear dest) ----
    #pragma unroll
    for (int i = 0; i < 8; i++) {
        const int base = i * 512 + w * 64;
        GLOAD_LDS16(xfrag + base + lane, (char*)afr + (size_t)base * 16);
    }
    __syncthreads();

    float thr = INF_F; int thrn = 0x7fffffff; int cnt = 0;

    for (int ti = 0; ti < tcount; ti++) {
        const int n0 = (t0 + ti) * 128;
        const int row = n0 + 16 * w + li;
        const size_t rowc = (size_t)(row < N ? row : N - 1);
        const float* bp = reps + rowc * 512 + q * 8;

        // ---- burst-preload the lane's full k-slice: 32 independent loads ----
        float4 yv[32];
        #pragma unroll
        for (int i = 0; i < 32; i++)
            yv[i] = *(const float4*)(bp + (i >> 1) * 32 + (i & 1) * 4);

        f32x4 acc0 = {0.f,0.f,0.f,0.f}, acc1 = {0.f,0.f,0.f,0.f};
        f32x4 acc2 = {0.f,0.f,0.f,0.f}, acc3 = {0.f,0.f,0.f,0.f};
        float ynacc = 0.f;

        #pragma unroll
        for (int ks = 0; ks < 16; ks++) {
            const float4 y0 = yv[2 * ks];
            const float4 y1 = yv[2 * ks + 1];
            ynacc = fmaf(y0.x, y0.x, fmaf(y0.y, y0.y, fmaf(y0.z, y0.z, fmaf(y0.w, y0.w, ynacc))));
            ynacc = fmaf(y1.x, y1.x, fmaf(y1.y, y1.y, fmaf(y1.z, y1.z, fmaf(y1.w, y1.w, ynacc))));
            const auto p0 = __builtin_amdgcn_cvt_pkrtz(y0.x, y0.y);
            const auto p1 = __builtin_amdgcn_cvt_pkrtz(y0.z, y0.w);
            const auto p2 = __builtin_amdgcn_cvt_pkrtz(y1.x, y1.y);
            const auto p3 = __builtin_amdgcn_cvt_pkrtz(y1.z, y1.w);
            uint4 bu;
            bu.x = __builtin_bit_cast(unsigned, p0);
            bu.y = __builtin_bit_cast(unsigned, p1);
            bu.z = __builtin_bit_cast(unsigned, p2);
            bu.w = __builtin_bit_cast(unsigned, p3);
            const f16x8 bf = __builtin_bit_cast(f16x8, bu);
            const uint4 a0u = afr[(ks * 4 + 0) * 64 + lane];
            const uint4 a1u = afr[(ks * 4 + 1) * 64 + lane];
            const uint4 a2u = afr[(ks * 4 + 2) * 64 + lane];
            const uint4 a3u = afr[(ks * 4 + 3) * 64 + lane];
            acc0 = __builtin_amdgcn_mfma_f32_16x16x32_f16(__builtin_bit_cast(f16x8, a0u), bf, acc0, 0, 0, 0);
            acc1 = __builtin_amdgcn_mfma_f32_16x16x32_f16(__builtin_bit_cast(f16x8, a1u), bf, acc1, 0, 0, 0);
            acc2 = __builtin_amdgcn_mfma_f32_16x16x32_f16(__builtin_bit_cast(f16x8, a2u), bf, acc2, 0, 0, 0);
            acc3 = __builtin_amdgcn_mfma_f32_16x16x32_f16(__builtin_bit_cast(f16x8, a3u), bf, acc3, 0, 0, 0);
        }
        // full ||y||^2 for this lane's row (reduce across the 4 k-quarters)
        ynacc += __shfl_xor(ynacc, 16);
        ynacc += __shfl_xor(ynacc, 32);
        const float yn = (row < N) ? ynacc : INF_F;   // invalid rows -> +inf s

        __syncthreads();   // A: previous tile's scan has finished with slds

        // D layout: col n = lane&15, row m(within 16) = 4*q + reg
        {
            const int nl = 16 * w + li;
            float4 sv;
            sv.x = fmaf(-2.f, acc0[0], yn); sv.y = fmaf(-2.f, acc0[1], yn);
            sv.z = fmaf(-2.f, acc0[2], yn); sv.w = fmaf(-2.f, acc0[3], yn);
            *(float4*)(&slds[nl][0  + 4 * q]) = sv;
            sv.x = fmaf(-2.f, acc1[0], yn); sv.y = fmaf(-2.f, acc1[1], yn);
            sv.z = fmaf(-2.f, acc1[2], yn); sv.w = fmaf(-2.f, acc1[3], yn);
            *(float4*)(&slds[nl][16 + 4 * q]) = sv;
            sv.x = fmaf(-2.f, acc2[0], yn); sv.y = fmaf(-2.f, acc2[1], yn);
            sv.z = fmaf(-2.f, acc2[2], yn); sv.w = fmaf(-2.f, acc2[3], yn);
            *(float4*)(&slds[nl][32 + 4 * q]) = sv;
            sv.x = fmaf(-2.f, acc3[0], yn); sv.y = fmaf(-2.f, acc3[1], yn);
            sv.z = fmaf(-2.f, acc3[2], yn); sv.w = fmaf(-2.f, acc3[3], yn);
            *(float4*)(&slds[nl][48 + 4 * q]) = sv;
        }
        __syncthreads();   // B: s-matrix ready

        // per-row top-16 scan; thread r owns batch row r (register threshold);
        // overlaps with waves 1..7 running the next tile's k-loop.
        if (tid < 64) {
            const int r = tid;
            #pragma unroll 2
            for (int j = 0; j < 128; j++) {
                const float s = slds[j][r];
                const int n = n0 + j;
                if (lexLess(s, n, thr, thrn)) {
                    if (cnt < 16) {
                        topd[cnt][r] = s; topi[cnt][r] = n; cnt++;
                        if (cnt == 16) {
                            float tv = topd[0][r]; int tn = topi[0][r];
                            #pragma unroll
                            for (int u = 1; u < 16; u++) {
                                float v = topd[u][r]; int nn = topi[u][r];
                                if (!lexLess(v, nn, tv, tn)) { tv = v; tn = nn; }
                            }
                            thr = tv; thrn = tn;
                        }
                    } else {
                        #pragma unroll
                        for (int u = 0; u < 16; u++)
                            if (topd[u][r] == thr && topi[u][r] == thrn) {
                                topd[u][r] = s; topi[u][r] = n; break;
                            }
                        float tv = topd[0][r]; int tn = topi[0][r];
                        #pragma unroll
                        for (int u = 1; u < 16; u++) {
                            float v = topd[u][r]; int nn = topi[u][r];
                            if (!lexLess(v, nn, tv, tn)) { tv = v; tn = nn; }
                        }
                        thr = tv; thrn = tn;
                    }
                }
            }
        }
    }

    if (tid < 64) {
        const size_t base = ((size_t)b * 64 + tid) * 16;
        for (int j = 0; j < 16; j++) {
            cs[base + j] = (j < cnt) ? topd[j][tid] : INF_F;
            ci[base + j] = (j < cnt) ? topi[j][tid] : 0x7fffffff;
        }
    }
}

// ---------------------------------------------------------------------------
// Kernel 2: per batch row — approx global top-24 merge, fp64 exact recompute,
// exact sort -> top-16, softmax weights, action gather, outputs.
// ---------------------------------------------------------------------------
__global__ __launch_bounds__(256) void merge_kernel(
    const float* __restrict__ cs, const int* __restrict__ ci,
    const float* __restrict__ brep, const float* __restrict__ reps,
    const float* __restrict__ acts,
    float* __restrict__ out, int NBLK, int N, int BA)
{
    const int r = blockIdx.x;
    const int tid = threadIdx.x;
    __shared__ __align__(16) float xrow[512];
    __shared__ float S1s[256 * KM];
    __shared__ int   S1i[256 * KM];
    __shared__ float S2s[32 * KM];
    __shared__ int   S2i[32 * KM];
    __shared__ double fd[KM];
    __shared__ int    fn[KM];

    if (tid < 128)
        *(float4*)(&xrow[tid * 4]) = *(const float4*)(&brep[(size_t)r * 512 + tid * 4]);

    float ls[KM]; int li[KM];
    #pragma unroll
    for (int j = 0; j < KM; j++) { ls[j] = INF_F; li[j] = 0x7fffffff; }
    float mv = INF_F; int mn = 0x7fffffff; int mp = 0;
    const int total = NBLK * 16;
    for (int e = tid; e < total; e += 256) {
        const int blk = e >> 4, j = e & 15;
        const size_t a = (size_t)blk * 1024 + (size_t)r * 16 + j;
        const float s = cs[a]; const int n = ci[a];
        if (lexLess(s, n, mv, mn)) {
            ls[mp] = s; li[mp] = n;
            mv = ls[0]; mn = li[0]; mp = 0;
            #pragma unroll
            for (int u = 1; u < KM; u++)
                if (!lexLess(ls[u], li[u], mv, mn)) { mv = ls[u]; mn = li[u]; mp = u; }
        }
    }
    #pragma unroll
    for (int j = 0; j < KM; j++) { S1s[tid * KM + j] = ls[j]; S1i[tid * KM + j] = li[j]; }
    __syncthreads();

    if (tid < 32) {
        #pragma unroll
        for (int j = 0; j < KM; j++) { ls[j] = INF_F; li[j] = 0x7fffffff; }
        mv = INF_F; mn = 0x7fffffff; mp = 0;
        for (int e = tid * 8 * KM; e < (tid * 8 + 8) * KM; e++) {
            const float s = S1s[e]; const int n = S1i[e];
            if (lexLess(s, n, mv, mn)) {
                ls[mp] = s; li[mp] = n;
                mv = ls[0]; mn = li[0]; mp = 0;
                #pragma unroll
                for (int u = 1; u < KM; u++)
                    if (!lexLess(ls[u], li[u], mv, mn)) { mv = ls[u]; mn = li[u]; mp = u; }
            }
        }
        #pragma unroll
        for (int j = 0; j < KM; j++) { S2s[tid * KM + j] = ls[j]; S2i[tid * KM + j] = li[j]; }
    }
    __syncthreads();

    if (tid == 0) {
        #pragma unroll
        for (int j = 0; j < KM; j++) { ls[j] = INF_F; li[j] = 0x7fffffff; }
        mv = INF_F; mn = 0x7fffffff; mp = 0;
        for (int e = 0; e < 32 * KM; e++) {
            const float s = S2s[e]; const int n = S2i[e];
            if (lexLess(s, n, mv, mn)) {
                ls[mp] = s; li[mp] = n;
                mv = ls[0]; mn = li[0]; mp = 0;
                #pragma unroll
                for (int u = 1; u < KM; u++)
                    if (!lexLess(ls[u], li[u], mv, mn)) { mv = ls[u]; mn = li[u]; mp = u; }
            }
        }
        for (int j = 0; j < KM; j++) fn[j] = li[j];
    }
    __syncthreads();

    if (tid < KM) {
        const int n = fn[tid];
        double d = 1.0e300;
        if (n >= 0 && n < N) {
            d = 0.0;
            const float* yp = reps + (size_t)n * 512;
            for (int i = 0; i < 512; i += 4) {
                float4 yv = *(const float4*)(yp + i);
                double d0 = (double)xrow[i + 0] - (double)yv.x;
                double d1 = (double)xrow[i + 1] - (double)yv.y;
                double d2 = (double)xrow[i + 2] - (double)yv.z;
                double d3 = (double)xrow[i + 3] - (double)yv.w;
                d += d0 * d0 + d1 * d1 + d2 * d2 + d3 * d3;
            }
        }
        fd[tid] = d;
    }
    __syncthreads();

    if (tid == 0) {
        int ord[KM];
        for (int j = 0; j < KM; j++) ord[j] = j;
        for (int a = 0; a < 16; a++) {
            int best = a;
            for (int u = a + 1; u < KM; u++) {
                const int ou = ord[u], ob = ord[best];
                if (fd[ou] < fd[ob] || (fd[ou] == fd[ob] && fn[ou] < fn[ob])) best = u;
            }
            int tmp = ord[a]; ord[a] = ord[best]; ord[best] = tmp;
        }
        double dist[16];
        for (int j = 0; j < 16; j++) {
            double v = fd[ord[j]];
            dist[j] = sqrt(v > 0.0 ? v : 0.0);
        }
        double wv[16], wsum = 0.0;
        for (int j = 0; j < 16; j++) { wv[j] = exp(dist[0] - dist[j]); wsum += wv[j]; }
        for (int a = 0; a < 7; a++) {
            double s = 0.0;
            for (int j = 0; j < 16; j++)
                s += wv[j] * (double)acts[(size_t)fn[ord[j]] * 7 + a];
            out[r * 7 + a] = (float)(s / wsum);
        }
        for (int j = 0; j < 16; j++)
            out[BA + r * 16 + j] = (float)fn[ord[j]];
    }
}

extern "C" void kernel_launch(void* const* d_in, const int* in_sizes, int n_in,
                              void* d_out, int out_size, void* d_ws, size_t ws_size,
                              hipStream_t stream) {
    const float* brep = (const float*)d_in[0];
    const float* reps = (const float*)d_in[1];
    const float* acts = (const float*)d_in[2];
    const int D = 512;
    const int B = in_sizes[0] / D;   // 64
    const int N = in_sizes[1] / D;   // 500000
    float* out = (float*)d_out;

    // workspace: cs [NBLK*64*16 f32] | ci [NBLK*64*16 i32] | xfrag [64KB]
    int NBLK = 512;                                   // 2 rounds of 1 block/CU
    const size_t perblk = (size_t)64 * 16 * 8;
    if ((size_t)NBLK * perblk + 65536 > ws_size)
        NBLK = (int)((ws_size - 65536) / perblk);
    if (NBLK < 1) NBLK = 1;

    float* cs = (float*)d_ws;
    int* ci = (int*)((char*)d_ws + (size_t)NBLK * 64 * 16 * 4);
    uint4* xfrag = (uint4*)((char*)d_ws + (size_t)NBLK * perblk);

    const int TT = (N + 127) / 128;                   // 128-row tiles
    const int tilesBase = TT / NBLK;
    const int tilesRem = TT % NBLK;

    prepack_kernel<<<16, 256, 0, stream>>>(brep, xfrag);
    dist_topk_kernel<<<NBLK, 512, 0, stream>>>(reps, xfrag, cs, ci, N, tilesBase, tilesRem);
    merge_kernel<<<B, 256, 0, stream>>>(cs, ci, brep, reps, acts, out, NBLK, N, B * 7);
}

// Round 6
// 1528.530 us; speedup vs baseline: 1.7525x; 1.7525x over previous
//
#include <hip/hip_runtime.h>
#include <stdint.h>

typedef _Float16 f16;
typedef _Float16 f16x8 __attribute__((ext_vector_type(8)));
typedef float f32x4 __attribute__((ext_vector_type(4)));

#define INF_F __builtin_inff()
#define KM 24   // merge candidate margin

__device__ __forceinline__ bool lexLess(float s1, int n1, float s2, int n2) {
    return (s1 < s2) || (s1 == s2 && n1 < n2);
}

// ---------------------------------------------------------------------------
// Kernel 0: pack brep [64,512] f32 -> f16 MFMA A-fragments, COALESCED layout:
// xfrag[(ks*4+ms)*64 + lane] = uint4 of A[m=ms*16+(lane&15)]
// [k = ks*32 + (lane>>4)*8 + j], j=0..7.  Lane-contiguous 1KB per (ks,ms).
// ---------------------------------------------------------------------------
__global__ __launch_bounds__(256) void prepack_kernel(
    const float* __restrict__ brep, uint4* __restrict__ xfrag)
{
    const int e = blockIdx.x * 256 + threadIdx.x;   // 0..4095
    if (e >= 4096) return;
    const int lane = e & 63;
    const int ms = (e >> 6) & 3;
    const int ks = e >> 8;
    const int m = ms * 16 + (lane & 15);
    const int k = ks * 32 + (lane >> 4) * 8;
    const float* src = brep + m * 512 + k;
    unsigned short hb[8];
    #pragma unroll
    for (int j = 0; j < 8; j++) {
        f16 v = (f16)src[j];                         // RTN
        hb[j] = __builtin_bit_cast(unsigned short, v);
    }
    uint4 o;
    o.x = (unsigned)hb[0] | ((unsigned)hb[1] << 16);
    o.y = (unsigned)hb[2] | ((unsigned)hb[3] << 16);
    o.z = (unsigned)hb[4] | ((unsigned)hb[5] << 16);
    o.w = (unsigned)hb[6] | ((unsigned)hb[7] << 16);
    xfrag[e] = o;
}

// ---------------------------------------------------------------------------
// Kernel 1: 256 threads / 4 waves, 64-row tiles, 16 waves/CU target.
// Wave w owns reps rows [n0+16w, +16). Per kstep: 2 coalesced-ish y-loads
// (HBM) + 4 fully-coalesced 1KB a-loads (L2-hot xfrag), depth-1 software
// rotation so loads of kstep+1 are in flight during kstep's MFMA.
// s = ||y||^2 - 2 x.y -> slds [n][m]; the scanning wave rotates per tile
// (threshold state in LDS) and keeps exact per-block top-16 per batch row.
// ---------------------------------------------------------------------------
__global__ __launch_bounds__(256, 4) void dist_topk_kernel(
    const float* __restrict__ reps, const uint4* __restrict__ xfrag,
    float* __restrict__ cs, int* __restrict__ ci,
    int N, int tilesBase, int tilesRem)
{
    __shared__ __align__(16) float slds[64][68];   // 17.4 KB
    __shared__ float topd[16][64];                 // 4 KB
    __shared__ int   topi[16][64];                 // 4 KB
    __shared__ float thrS[64];
    __shared__ int   thrnS[64];
    __shared__ int   cntS[64];

    const int tid = threadIdx.x;
    const int w = tid >> 6, lane = tid & 63;
    const int li = lane & 15, q = lane >> 4;
    const int b = blockIdx.x;
    const int t0 = b * tilesBase + min(b, tilesRem);
    const int tcount = tilesBase + (b < tilesRem ? 1 : 0);

    if (tid < 64) { thrS[tid] = INF_F; thrnS[tid] = 0x7fffffff; cntS[tid] = 0; }
    __syncthreads();

    for (int ti = 0; ti < tcount; ti++) {
        const int n0 = (t0 + ti) * 64;
        const int row = n0 + 16 * w + li;
        const size_t rowc = (size_t)(row < N ? row : N - 1);
        const float* bp = reps + rowc * 512 + q * 8;

        f32x4 acc0 = {0.f,0.f,0.f,0.f}, acc1 = {0.f,0.f,0.f,0.f};
        f32x4 acc2 = {0.f,0.f,0.f,0.f}, acc3 = {0.f,0.f,0.f,0.f};
        float ynacc = 0.f;

        // ---- depth-1 rotated k-loop: loads of ks+1 in flight over MFMA of ks
        float4 yA0 = *(const float4*)(bp);
        float4 yA1 = *(const float4*)(bp + 4);
        uint4 aA0 = xfrag[(0 * 4 + 0) * 64 + lane];
        uint4 aA1 = xfrag[(0 * 4 + 1) * 64 + lane];
        uint4 aA2 = xfrag[(0 * 4 + 2) * 64 + lane];
        uint4 aA3 = xfrag[(0 * 4 + 3) * 64 + lane];

        #pragma unroll
        for (int ks = 0; ks < 16; ks++) {
            float4 yB0, yB1;
            uint4 aB0, aB1, aB2, aB3;
            if (ks < 15) {
                yB0 = *(const float4*)(bp + (ks + 1) * 32);
                yB1 = *(const float4*)(bp + (ks + 1) * 32 + 4);
                aB0 = xfrag[((ks + 1) * 4 + 0) * 64 + lane];
                aB1 = xfrag[((ks + 1) * 4 + 1) * 64 + lane];
                aB2 = xfrag[((ks + 1) * 4 + 2) * 64 + lane];
                aB3 = xfrag[((ks + 1) * 4 + 3) * 64 + lane];
            }
            ynacc = fmaf(yA0.x, yA0.x, fmaf(yA0.y, yA0.y, fmaf(yA0.z, yA0.z, fmaf(yA0.w, yA0.w, ynacc))));
            ynacc = fmaf(yA1.x, yA1.x, fmaf(yA1.y, yA1.y, fmaf(yA1.z, yA1.z, fmaf(yA1.w, yA1.w, ynacc))));
            const auto p0 = __builtin_amdgcn_cvt_pkrtz(yA0.x, yA0.y);
            const auto p1 = __builtin_amdgcn_cvt_pkrtz(yA0.z, yA0.w);
            const auto p2 = __builtin_amdgcn_cvt_pkrtz(yA1.x, yA1.y);
            const auto p3 = __builtin_amdgcn_cvt_pkrtz(yA1.z, yA1.w);
            uint4 bu;
            bu.x = __builtin_bit_cast(unsigned, p0);
            bu.y = __builtin_bit_cast(unsigned, p1);
            bu.z = __builtin_bit_cast(unsigned, p2);
            bu.w = __builtin_bit_cast(unsigned, p3);
            const f16x8 bf = __builtin_bit_cast(f16x8, bu);
            acc0 = __builtin_amdgcn_mfma_f32_16x16x32_f16(__builtin_bit_cast(f16x8, aA0), bf, acc0, 0, 0, 0);
            acc1 = __builtin_amdgcn_mfma_f32_16x16x32_f16(__builtin_bit_cast(f16x8, aA1), bf, acc1, 0, 0, 0);
            acc2 = __builtin_amdgcn_mfma_f32_16x16x32_f16(__builtin_bit_cast(f16x8, aA2), bf, acc2, 0, 0, 0);
            acc3 = __builtin_amdgcn_mfma_f32_16x16x32_f16(__builtin_bit_cast(f16x8, aA3), bf, acc3, 0, 0, 0);
            if (ks < 15) {
                yA0 = yB0; yA1 = yB1;
                aA0 = aB0; aA1 = aB1; aA2 = aB2; aA3 = aB3;
            }
        }

        // full ||y||^2 for this lane's row (reduce across the 4 k-quarters)
        ynacc += __shfl_xor(ynacc, 16);
        ynacc += __shfl_xor(ynacc, 32);
        const float yn = (row < N) ? ynacc : INF_F;   // pad rows -> +inf s

        __syncthreads();   // A: previous tile's scan has finished with slds

        // D layout: col n = lane&15 (rep row), row m = 16*ms + 4*q + reg (batch)
        {
            const int nl = 16 * w + li;
            float4 sv;
            sv.x = fmaf(-2.f, acc0[0], yn); sv.y = fmaf(-2.f, acc0[1], yn);
            sv.z = fmaf(-2.f, acc0[2], yn); sv.w = fmaf(-2.f, acc0[3], yn);
            *(float4*)(&slds[nl][0  + 4 * q]) = sv;
            sv.x = fmaf(-2.f, acc1[0], yn); sv.y = fmaf(-2.f, acc1[1], yn);
            sv.z = fmaf(-2.f, acc1[2], yn); sv.w = fmaf(-2.f, acc1[3], yn);
            *(float4*)(&slds[nl][16 + 4 * q]) = sv;
            sv.x = fmaf(-2.f, acc2[0], yn); sv.y = fmaf(-2.f, acc2[1], yn);
            sv.z = fmaf(-2.f, acc2[2], yn); sv.w = fmaf(-2.f, acc2[3], yn);
            *(float4*)(&slds[nl][32 + 4 * q]) = sv;
            sv.x = fmaf(-2.f, acc3[0], yn); sv.y = fmaf(-2.f, acc3[1], yn);
            sv.z = fmaf(-2.f, acc3[2], yn); sv.w = fmaf(-2.f, acc3[3], yn);
            *(float4*)(&slds[nl][48 + 4 * q]) = sv;
        }
        __syncthreads();   // B: s-matrix ready

        // per-row top-16 scan; scanning wave rotates per tile, state in LDS
        if (w == (ti & 3)) {
            const int r = lane;
            float thr = thrS[r]; int thrn = thrnS[r]; int cnt = cntS[r];
            #pragma unroll 4
            for (int j = 0; j < 64; j++) {
                const float s = slds[j][r];
                const int n = n0 + j;
                if (lexLess(s, n, thr, thrn)) {
                    if (cnt < 16) {
                        topd[cnt][r] = s; topi[cnt][r] = n; cnt++;
                        if (cnt == 16) {
                            float tv = topd[0][r]; int tn = topi[0][r];
                            #pragma unroll
                            for (int u = 1; u < 16; u++) {
                                float v = topd[u][r]; int nn = topi[u][r];
                                if (!lexLess(v, nn, tv, tn)) { tv = v; tn = nn; }
                            }
                            thr = tv; thrn = tn;
                        }
                    } else {
                        #pragma unroll
                        for (int u = 0; u < 16; u++)
                            if (topd[u][r] == thr && topi[u][r] == thrn) {
                                topd[u][r] = s; topi[u][r] = n; break;
                            }
                        float tv = topd[0][r]; int tn = topi[0][r];
                        #pragma unroll
                        for (int u = 1; u < 16; u++) {
                            float v = topd[u][r]; int nn = topi[u][r];
                            if (!lexLess(v, nn, tv, tn)) { tv = v; tn = nn; }
                        }
                        thr = tv; thrn = tn;
                    }
                }
            }
            thrS[r] = thr; thrnS[r] = thrn; cntS[r] = cnt;
        }
    }

    __syncthreads();
    if (tid < 64) {
        const int c = cntS[tid];
        const size_t base = ((size_t)b * 64 + tid) * 16;
        for (int j = 0; j < 16; j++) {
            cs[base + j] = (j < c) ? topd[j][tid] : INF_F;
            ci[base + j] = (j < c) ? topi[j][tid] : 0x7fffffff;
        }
    }
}

// ---------------------------------------------------------------------------
// Kernel 2: per batch row — approx global top-24 merge, fp64 exact recompute,
// exact sort -> top-16, softmax weights, action gather, outputs.
// ---------------------------------------------------------------------------
__global__ __launch_bounds__(256) void merge_kernel(
    const float* __restrict__ cs, const int* __restrict__ ci,
    const float* __restrict__ brep, const float* __restrict__ reps,
    const float* __restrict__ acts,
    float* __restrict__ out, int NBLK, int N, int BA)
{
    const int r = blockIdx.x;
    const int tid = threadIdx.x;
    __shared__ __align__(16) float xrow[512];
    __shared__ float S1s[256 * KM];
    __shared__ int   S1i[256 * KM];
    __shared__ float S2s[32 * KM];
    __shared__ int   S2i[32 * KM];
    __shared__ double fd[KM];
    __shared__ int    fn[KM];

    if (tid < 128)
        *(float4*)(&xrow[tid * 4]) = *(const float4*)(&brep[(size_t)r * 512 + tid * 4]);

    float ls[KM]; int li[KM];
    #pragma unroll
    for (int j = 0; j < KM; j++) { ls[j] = INF_F; li[j] = 0x7fffffff; }
    float mv = INF_F; int mn = 0x7fffffff; int mp = 0;
    const int total = NBLK * 16;
    for (int e = tid; e < total; e += 256) {
        const int blk = e >> 4, j = e & 15;
        const size_t a = (size_t)blk * 1024 + (size_t)r * 16 + j;
        const float s = cs[a]; const int n = ci[a];
        if (lexLess(s, n, mv, mn)) {
            ls[mp] = s; li[mp] = n;
            mv = ls[0]; mn = li[0]; mp = 0;
            #pragma unroll
            for (int u = 1; u < KM; u++)
                if (!lexLess(ls[u], li[u], mv, mn)) { mv = ls[u]; mn = li[u]; mp = u; }
        }
    }
    #pragma unroll
    for (int j = 0; j < KM; j++) { S1s[tid * KM + j] = ls[j]; S1i[tid * KM + j] = li[j]; }
    __syncthreads();

    if (tid < 32) {
        #pragma unroll
        for (int j = 0; j < KM; j++) { ls[j] = INF_F; li[j] = 0x7fffffff; }
        mv = INF_F; mn = 0x7fffffff; mp = 0;
        for (int e = tid * 8 * KM; e < (tid * 8 + 8) * KM; e++) {
            const float s = S1s[e]; const int n = S1i[e];
            if (lexLess(s, n, mv, mn)) {
                ls[mp] = s; li[mp] = n;
                mv = ls[0]; mn = li[0]; mp = 0;
                #pragma unroll
                for (int u = 1; u < KM; u++)
                    if (!lexLess(ls[u], li[u], mv, mn)) { mv = ls[u]; mn = li[u]; mp = u; }
            }
        }
        #pragma unroll
        for (int j = 0; j < KM; j++) { S2s[tid * KM + j] = ls[j]; S2i[tid * KM + j] = li[j]; }
    }
    __syncthreads();

    if (tid == 0) {
        #pragma unroll
        for (int j = 0; j < KM; j++) { ls[j] = INF_F; li[j] = 0x7fffffff; }
        mv = INF_F; mn = 0x7fffffff; mp = 0;
        for (int e = 0; e < 32 * KM; e++) {
            const float s = S2s[e]; const int n = S2i[e];
            if (lexLess(s, n, mv, mn)) {
                ls[mp] = s; li[mp] = n;
                mv = ls[0]; mn = li[0]; mp = 0;
                #pragma unroll
                for (int u = 1; u < KM; u++)
                    if (!lexLess(ls[u], li[u], mv, mn)) { mv = ls[u]; mn = li[u]; mp = u; }
            }
        }
        for (int j = 0; j < KM; j++) fn[j] = li[j];
    }
    __syncthreads();

    if (tid < KM) {
        const int n = fn[tid];
        double d = 1.0e300;
        if (n >= 0 && n < N) {
            d = 0.0;
            const float* yp = reps + (size_t)n * 512;
            for (int i = 0; i < 512; i += 4) {
                float4 yv = *(const float4*)(yp + i);
                double d0 = (double)xrow[i + 0] - (double)yv.x;
                double d1 = (double)xrow[i + 1] - (double)yv.y;
                double d2 = (double)xrow[i + 2] - (double)yv.z;
                double d3 = (double)xrow[i + 3] - (double)yv.w;
                d += d0 * d0 + d1 * d1 + d2 * d2 + d3 * d3;
            }
        }
        fd[tid] = d;
    }
    __syncthreads();

    if (tid == 0) {
        int ord[KM];
        for (int j = 0; j < KM; j++) ord[j] = j;
        for (int a = 0; a < 16; a++) {
            int best = a;
            for (int u = a + 1; u < KM; u++) {
                const int ou = ord[u], ob = ord[best];
                if (fd[ou] < fd[ob] || (fd[ou] == fd[ob] && fn[ou] < fn[ob])) best = u;
            }
            int tmp = ord[a]; ord[a] = ord[best]; ord[best] = tmp;
        }
        double dist[16];
        for (int j = 0; j < 16; j++) {
            double v = fd[ord[j]];
            dist[j] = sqrt(v > 0.0 ? v : 0.0);
        }
        double wv[16], wsum = 0.0;
        for (int j = 0; j < 16; j++) { wv[j] = exp(dist[0] - dist[j]); wsum += wv[j]; }
        for (int a = 0; a < 7; a++) {
            double s = 0.0;
            for (int j = 0; j < 16; j++)
                s += wv[j] * (double)acts[(size_t)fn[ord[j]] * 7 + a];
            out[r * 7 + a] = (float)(s / wsum);
        }
        for (int j = 0; j < 16; j++)
            out[BA + r * 16 + j] = (float)fn[ord[j]];
    }
}

extern "C" void kernel_launch(void* const* d_in, const int* in_sizes, int n_in,
                              void* d_out, int out_size, void* d_ws, size_t ws_size,
                              hipStream_t stream) {
    const float* brep = (const float*)d_in[0];
    const float* reps = (const float*)d_in[1];
    const float* acts = (const float*)d_in[2];
    const int D = 512;
    const int B = in_sizes[0] / D;   // 64
    const int N = in_sizes[1] / D;   // 500000
    float* out = (float*)d_out;

    // workspace: cs [NBLK*64*16 f32] | ci [NBLK*64*16 i32] | xfrag [64KB]
    int NBLK = 1024;                                  // 4 blocks/CU x 256 CU
    const size_t perblk = (size_t)64 * 16 * 8;
    if ((size_t)NBLK * perblk + 65536 > ws_size)
        NBLK = (int)((ws_size - 65536) / perblk);
    if (NBLK < 1) NBLK = 1;

    float* cs = (float*)d_ws;
    int* ci = (int*)((char*)d_ws + (size_t)NBLK * 64 * 16 * 4);
    uint4* xfrag = (uint4*)((char*)d_ws + (size_t)NBLK * perblk);

    const int TT = (N + 63) / 64;                     // 64-row tiles
    const int tilesBase = TT / NBLK;
    const int tilesRem = TT % NBLK;

    prepack_kernel<<<16, 256, 0, stream>>>(brep, xfrag);
    dist_topk_kernel<<<NBLK, 256, 0, stream>>>(reps, xfrag, cs, ci, N, tilesBase, tilesRem);
    merge_kernel<<<B, 256, 0, stream>>>(cs, ci, brep, reps, acts, out, NBLK, N, B * 7);
}